// Round 8
// baseline (652.094 us; speedup 1.0000x reference)
//
#include <hip/hip_runtime.h>
#include <math.h>

#define NB   128
#define CCH  512
#define HW   784      // 28*28
#define NCLS 1000
#define BPI  32       // blocks per image
#define CPB  16       // channels per block
#define FPB4 3136     // f32x4 per block slab = 16*196

typedef float f32x4 __attribute__((ext_vector_type(4)));

// Single-feat-read kernel. Block (n, q) stages 16 channels of image n in LDS,
// contributes its channel means to pooled (disjoint writes), syncs with the
// other 31 blocks of image n via a device-scope counter, computes the image's
// softmax mask redundantly, then multiplies its LDS slab and streams out.
__global__ __launch_bounds__(256) void k_main(const float* __restrict__ feat,
                                              const int* __restrict__ y,
                                              const float* __restrict__ w,
                                              float* __restrict__ out,
                                              float* __restrict__ pooled,
                                              unsigned* __restrict__ cnt) {
    __shared__ f32x4 sdata[FPB4];      // 50176 B slab
    __shared__ float red[8];
    __shared__ float smrow[CCH];       // full mask row of this image

    const int t = threadIdx.x, lane = t & 63, wv = t >> 6;
    const int n = blockIdx.x >> 5;     // image, 0..127
    const int q = blockIdx.x & 31;     // channel slab, 0..31

    const size_t base4 = ((size_t)n * CCH + q * CPB) * (HW / 4);
    const f32x4* src4 = reinterpret_cast<const f32x4*>(feat) + base4;

    // ---- A: stage slab into LDS ----
    for (int i = t; i < FPB4; i += 256) sdata[i] = src4[i];
    __syncthreads();

    // ---- channel means: 16 threads per channel, stride-16 f32x4 partials ----
    {
        int ch = t >> 4, p = t & 15;
        const f32x4* cb = sdata + ch * 196;
        float s = 0.f;
        for (int j = p; j < 196; j += 16) { f32x4 v = cb[j]; s += v.x + v.y + v.z + v.w; }
        s += __shfl_xor(s, 1, 64); s += __shfl_xor(s, 2, 64);
        s += __shfl_xor(s, 4, 64); s += __shfl_xor(s, 8, 64);
        if (p == 0) pooled[(size_t)n * CCH + q * CPB + ch] = s * (1.0f / 784.0f);
    }
    __threadfence();                   // release pooled stores (device scope)
    __syncthreads();

    // ---- per-image arrival counter; spin until all 32 slabs contributed ----
    if (t == 0) {
        __hip_atomic_fetch_add(&cnt[n], 1u, __ATOMIC_ACQ_REL, __HIP_MEMORY_SCOPE_AGENT);
        while (__hip_atomic_load(&cnt[n], __ATOMIC_ACQUIRE, __HIP_MEMORY_SCOPE_AGENT) < BPI)
            __builtin_amdgcn_s_sleep(1);
    }
    __syncthreads();

    // ---- B: full 512-channel mask, redundant per block (thread: c=t, c=t+256) ----
    {
        int cls = y[n];
        float p0 = pooled[(size_t)n * CCH + t];
        float p1 = pooled[(size_t)n * CCH + t + 256];
        float g0 = w[(size_t)cls * CCH + t] * p0;
        float g1 = w[(size_t)cls * CCH + t + 256] * p1;

        float ss = g0 * g0 + g1 * g1;
#pragma unroll
        for (int o = 32; o; o >>= 1) ss += __shfl_down(ss, o, 64);
        if (lane == 0) red[wv] = ss;
        __syncthreads();
        if (t == 0) red[4] = sqrtf(red[0] + red[1] + red[2] + red[3]);
        __syncthreads();
        float inv = 11.313708498984761f / red[4];   // sqrt(512)/2 / norm
        float v0 = 1.0f + g0 * inv, v1 = 1.0f + g1 * inv;
        __syncthreads();

        float mx = fmaxf(v0, v1);
#pragma unroll
        for (int o = 32; o; o >>= 1) mx = fmaxf(mx, __shfl_down(mx, o, 64));
        if (lane == 0) red[wv] = mx;
        __syncthreads();
        if (t == 0) red[4] = fmaxf(fmaxf(red[0], red[1]), fmaxf(red[2], red[3]));
        __syncthreads();
        float mmax = red[4];
        float e0 = expf(v0 - mmax), e1 = expf(v1 - mmax);
        __syncthreads();

        float se = e0 + e1;
#pragma unroll
        for (int o = 32; o; o >>= 1) se += __shfl_down(se, o, 64);
        if (lane == 0) red[wv] = se;
        __syncthreads();
        if (t == 0) red[4] = red[0] + red[1] + red[2] + red[3];
        __syncthreads();
        float is = 1.0f / red[4];
        smrow[t] = e0 * is;
        smrow[t + 256] = e1 * is;
        __syncthreads();
    }

    // ---- C: multiply LDS slab by mask, nontemporal stream out ----
    {
        f32x4* dst4 = reinterpret_cast<f32x4*>(out) + base4;
        for (int i = t; i < FPB4; i += 256) {
            float m = smrow[q * CPB + (unsigned)i / 196u];
            f32x4 v = sdata[i];
            v.x *= m; v.y *= m; v.z *= m; v.w *= m;
            __builtin_nontemporal_store(v, dst4 + i);
        }
    }
}

// Pred linear (round-3 proven structure): 4000 blocks = 250 cls-grp x 16 n-grp.
__global__ __launch_bounds__(256) void k_pred(const float* __restrict__ pooled,
                                              const float* __restrict__ w,
                                              const float* __restrict__ b,
                                              float* __restrict__ pred) {
    __shared__ float sp[4096];
    int t = threadIdx.x, lane = t & 63, wv = t >> 6;
    int cb = blockIdx.x % 250;             // cls group
    int nb = blockIdx.x / 250;             // n group (8 images)
    const float* pbase = pooled + (size_t)nb * 8 * CCH;
#pragma unroll
    for (int k = 0; k < 4; ++k)
        *reinterpret_cast<f32x4*>(sp + k * 1024 + t * 4) =
            *reinterpret_cast<const f32x4*>(pbase + k * 1024 + t * 4);
    __syncthreads();

    int cls = cb * 4 + wv;
    const float* wr = w + (size_t)cls * CCH;
    f32x4 a0 = *reinterpret_cast<const f32x4*>(wr + lane * 8);
    f32x4 a1 = *reinterpret_cast<const f32x4*>(wr + lane * 8 + 4);
    float bias = b[cls];
    float s[8];
#pragma unroll
    for (int nn = 0; nn < 8; ++nn) {
        f32x4 p0 = *reinterpret_cast<const f32x4*>(sp + nn * CCH + lane * 8);
        f32x4 p1 = *reinterpret_cast<const f32x4*>(sp + nn * CCH + lane * 8 + 4);
        s[nn] = a0.x * p0.x + a0.y * p0.y + a0.z * p0.z + a0.w * p0.w
              + a1.x * p1.x + a1.y * p1.y + a1.z * p1.z + a1.w * p1.w;
    }
#pragma unroll
    for (int nn = 0; nn < 8; ++nn) {
        float v = s[nn];
#pragma unroll
        for (int o = 32; o; o >>= 1) v += __shfl_down(v, o, 64);
        if (lane == 0) pred[(size_t)(nb * 8 + nn) * NCLS + cls] = v + bias;
    }
}

extern "C" void kernel_launch(void* const* d_in, const int* in_sizes, int n_in,
                              void* d_out, int out_size, void* d_ws, size_t ws_size,
                              hipStream_t stream) {
    const float* feat = (const float*)d_in[0];
    const int*   y    = (const int*)d_in[1];
    const float* w    = (const float*)d_in[2];
    const float* b    = (const float*)d_in[3];

    float* out_feat = (float*)d_out;                       // 128*512*784
    float* out_pred = out_feat + (size_t)NB * CCH * HW;    // 128*1000

    float* pooled = (float*)d_ws;                          // 65536 floats
    unsigned* cnt = (unsigned*)((char*)d_ws + 65536 * sizeof(float));  // 128 ctrs

    hipMemsetAsync(cnt, 0, NB * sizeof(unsigned), stream);
    k_main<<<NB * BPI, 256, 0, stream>>>(feat, y, w, out_feat, pooled, cnt);
    k_pred<<<4000, 256, 0, stream>>>(pooled, w, b, out_pred);
}

// Round 10
// 335.859 us; speedup vs baseline: 1.9416x; 1.9416x over previous
//
#include <hip/hip_runtime.h>
#include <math.h>

#define NB   128
#define CCH  512
#define HW   784      // 28*28
#define NCLS 1000
#define BPI  16       // blocks per image
#define CPB  32       // channels per block
#define FPB4 6272     // f32x4 per slab = 32*196
#define CTR_STRIDE 32 // uints per image sync record (128 B line padding)

typedef float f32x4 __attribute__((ext_vector_type(4)));

// Single-feat-read kernel. Block (n,q) stages 32 channels of image n in LDS
// (100 KB), contributes channel means to pooled (disjoint), then syncs with the
// image's other 15 blocks via a padded per-image counter + write-once flag.
// After the flag, computes the image's 512-wide softmax mask redundantly and
// multiplies its LDS slab -> nontemporal store. feat is read from HBM once.
__global__ __launch_bounds__(256) void k_main(const float* __restrict__ feat,
                                              const int* __restrict__ y,
                                              const float* __restrict__ w,
                                              float* __restrict__ out,
                                              float* __restrict__ pooled,
                                              unsigned* __restrict__ sync) {
    __shared__ f32x4 sdata[FPB4];      // 100352 B slab
    __shared__ float red[8];
    __shared__ float smrow[CCH];       // full mask row of this image

    const int t = threadIdx.x, lane = t & 63, wv = t >> 6;
    const int n = blockIdx.x >> 4;     // image, 0..127
    const int q = blockIdx.x & 15;     // slab, 0..15
    unsigned* cnt  = sync + (size_t)n * CTR_STRIDE;       // arrival counter
    unsigned* flag = cnt + 16;                            // completion flag (own 64B)

    const size_t base4 = ((size_t)n * CCH + q * CPB) * (HW / 4);
    const f32x4* src4 = reinterpret_cast<const f32x4*>(feat) + base4;

    // ---- A: stage slab into LDS ----
    for (int i = t; i < FPB4; i += 256) sdata[i] = src4[i];
    __syncthreads();

    // ---- channel means: wave wv owns channels 8wv..8wv+7, lane-consecutive ----
#pragma unroll
    for (int cc = 0; cc < 8; ++cc) {               // 4 waves x 8 = 32 channels
        int ch = wv * 8 + cc;
        const f32x4* cb = sdata + ch * 196;
        float s = 0.f;
        for (int j = lane; j < 196; j += 64) { f32x4 v = cb[j]; s += v.x + v.y + v.z + v.w; }
#pragma unroll
        for (int o = 32; o; o >>= 1) s += __shfl_down(s, o, 64);
        if (lane == 0) pooled[(size_t)n * CCH + q * CPB + ch] = s * (1.0f / 784.0f);
    }
    __threadfence();                   // make pooled stores device-visible
    __syncthreads();

    // ---- per-image sync: padded counter, write-once flag, slow poll ----
    if (t == 0) {
        unsigned old = __hip_atomic_fetch_add(cnt, 1u, __ATOMIC_ACQ_REL,
                                              __HIP_MEMORY_SCOPE_AGENT);
        if (old == BPI - 1) {
            __hip_atomic_store(flag, 1u, __ATOMIC_RELEASE, __HIP_MEMORY_SCOPE_AGENT);
        } else {
            while (__hip_atomic_load(flag, __ATOMIC_ACQUIRE,
                                     __HIP_MEMORY_SCOPE_AGENT) == 0u)
                __builtin_amdgcn_s_sleep(8);
        }
    }
    __syncthreads();

    // ---- B: full 512-channel mask, redundant per block (c = t, t+256) ----
    {
        int cls = y[n];
        float p0 = pooled[(size_t)n * CCH + t];
        float p1 = pooled[(size_t)n * CCH + t + 256];
        float g0 = w[(size_t)cls * CCH + t] * p0;
        float g1 = w[(size_t)cls * CCH + t + 256] * p1;

        float ss = g0 * g0 + g1 * g1;
#pragma unroll
        for (int o = 32; o; o >>= 1) ss += __shfl_down(ss, o, 64);
        if (lane == 0) red[wv] = ss;
        __syncthreads();
        if (t == 0) red[4] = sqrtf(red[0] + red[1] + red[2] + red[3]);
        __syncthreads();
        float inv = 11.313708498984761f / red[4];     // sqrt(512)/2 / norm
        float v0 = 1.0f + g0 * inv, v1 = 1.0f + g1 * inv;
        __syncthreads();

        float mx = fmaxf(v0, v1);
#pragma unroll
        for (int o = 32; o; o >>= 1) mx = fmaxf(mx, __shfl_down(mx, o, 64));
        if (lane == 0) red[wv] = mx;
        __syncthreads();
        if (t == 0) red[4] = fmaxf(fmaxf(red[0], red[1]), fmaxf(red[2], red[3]));
        __syncthreads();
        float mmax = red[4];
        float e0 = expf(v0 - mmax), e1 = expf(v1 - mmax);
        __syncthreads();

        float se = e0 + e1;
#pragma unroll
        for (int o = 32; o; o >>= 1) se += __shfl_down(se, o, 64);
        if (lane == 0) red[wv] = se;
        __syncthreads();
        if (t == 0) red[4] = red[0] + red[1] + red[2] + red[3];
        __syncthreads();
        float is = 1.0f / red[4];
        smrow[t] = e0 * is;
        smrow[t + 256] = e1 * is;
        __syncthreads();
    }

    // ---- C: multiply LDS slab by mask, nontemporal stream out ----
    {
        f32x4* dst4 = reinterpret_cast<f32x4*>(out) + base4;
        const float* sm = smrow + q * CPB;
        for (int i = t; i < FPB4; i += 256) {
            float m = sm[(unsigned)i / 196u];
            f32x4 v = sdata[i];
            v.x *= m; v.y *= m; v.z *= m; v.w *= m;
            __builtin_nontemporal_store(v, dst4 + i);
        }
    }
}

// Pred linear: 4000 blocks = 250 cls-grp x 16 n-grp (proven round-3 structure).
__global__ __launch_bounds__(256) void k_pred(const float* __restrict__ pooled,
                                              const float* __restrict__ w,
                                              const float* __restrict__ b,
                                              float* __restrict__ pred) {
    __shared__ float sp[4096];
    int t = threadIdx.x, lane = t & 63, wv = t >> 6;
    int cb = blockIdx.x % 250;             // cls group
    int nb = blockIdx.x / 250;             // n group (8 images)
    const float* pbase = pooled + (size_t)nb * 8 * CCH;
#pragma unroll
    for (int k = 0; k < 4; ++k)
        *reinterpret_cast<f32x4*>(sp + k * 1024 + t * 4) =
            *reinterpret_cast<const f32x4*>(pbase + k * 1024 + t * 4);
    __syncthreads();

    int cls = cb * 4 + wv;
    const float* wr = w + (size_t)cls * CCH;
    f32x4 a0 = *reinterpret_cast<const f32x4*>(wr + lane * 8);
    f32x4 a1 = *reinterpret_cast<const f32x4*>(wr + lane * 8 + 4);
    float bias = b[cls];
    float s[8];
#pragma unroll
    for (int nn = 0; nn < 8; ++nn) {
        f32x4 p0 = *reinterpret_cast<const f32x4*>(sp + nn * CCH + lane * 8);
        f32x4 p1 = *reinterpret_cast<const f32x4*>(sp + nn * CCH + lane * 8 + 4);
        s[nn] = a0.x * p0.x + a0.y * p0.y + a0.z * p0.z + a0.w * p0.w
              + a1.x * p1.x + a1.y * p1.y + a1.z * p1.z + a1.w * p1.w;
    }
#pragma unroll
    for (int nn = 0; nn < 8; ++nn) {
        float v = s[nn];
#pragma unroll
        for (int o = 32; o; o >>= 1) v += __shfl_down(v, o, 64);
        if (lane == 0) pred[(size_t)(nb * 8 + nn) * NCLS + cls] = v + bias;
    }
}

extern "C" void kernel_launch(void* const* d_in, const int* in_sizes, int n_in,
                              void* d_out, int out_size, void* d_ws, size_t ws_size,
                              hipStream_t stream) {
    const float* feat = (const float*)d_in[0];
    const int*   y    = (const int*)d_in[1];
    const float* w    = (const float*)d_in[2];
    const float* b    = (const float*)d_in[3];

    float* out_feat = (float*)d_out;                       // 128*512*784
    float* out_pred = out_feat + (size_t)NB * CCH * HW;    // 128*1000

    float* pooled = (float*)d_ws;                          // 65536 floats
    unsigned* sync = (unsigned*)((char*)d_ws + 65536 * sizeof(float));

    hipMemsetAsync(sync, 0, NB * CTR_STRIDE * sizeof(unsigned), stream);
    k_main<<<NB * BPI, 256, 0, stream>>>(feat, y, w, out_feat, pooled, sync);
    k_pred<<<4000, 256, 0, stream>>>(pooled, w, b, out_pred);
}

// Round 11
// 108.989 us; speedup vs baseline: 5.9831x; 3.0816x over previous
//
#include <hip/hip_runtime.h>
#include <math.h>

#define NB   128
#define CCH  512
#define HW   784      // 28*28
#define NCLS 1000
#define TOT4 12845056 // 128*512*784/4
#define AB   50176    // apply blocks = TOT4/256
#define PREDB 4000    // pred blocks = 250 cls-grp x 16 n-grp

typedef float f32x4 __attribute__((ext_vector_type(4)));

// K1: pooled[n*C+c] = mean over HW. One wave per channel, 4 waves/block.
__global__ __launch_bounds__(256) void k_pool(const float* __restrict__ feat,
                                              float* __restrict__ pooled) {
    int wv = threadIdx.x >> 6, lane = threadIdx.x & 63;
    int ch = blockIdx.x * 4 + wv;              // flat (n,c), < 65536
    const float* src = feat + (size_t)ch * HW;
    float s = 0.f;
#pragma unroll
    for (int it = 0; it < 3; ++it) {           // 3 * 256 floats
        f32x4 v = *reinterpret_cast<const f32x4*>(src + it * 256 + lane * 4);
        s += v.x + v.y + v.z + v.w;
    }
    if (lane < 4) {                            // last 16 floats
        f32x4 v = *reinterpret_cast<const f32x4*>(src + 768 + lane * 4);
        s += v.x + v.y + v.z + v.w;
    }
#pragma unroll
    for (int o = 32; o; o >>= 1) s += __shfl_down(s, o, 64);
    if (lane == 0) pooled[ch] = s * (1.0f / 784.0f);
}

// K2: mask only, one 256-thread block per image (c = t and t+256).
__global__ __launch_bounds__(256) void k_mask(const float* __restrict__ pooled,
                                              const float* __restrict__ w,
                                              const int* __restrict__ y,
                                              float* __restrict__ mask) {
    __shared__ float red[8];
    int t = threadIdx.x, lane = t & 63, wv = t >> 6;
    int n = blockIdx.x;
    int cls = y[n];
    const float* wr = w + (size_t)cls * CCH;
    const float* pr = pooled + (size_t)n * CCH;
    float g0 = wr[t] * pr[t];
    float g1 = wr[t + 256] * pr[t + 256];

    float ss = g0 * g0 + g1 * g1;
#pragma unroll
    for (int o = 32; o; o >>= 1) ss += __shfl_down(ss, o, 64);
    if (lane == 0) red[wv] = ss;
    __syncthreads();
    if (t == 0) red[4] = sqrtf(red[0] + red[1] + red[2] + red[3]);
    __syncthreads();
    float inv = 11.313708498984761f / red[4];   // sqrt(512)/2 / norm
    float v0 = 1.0f + g0 * inv, v1 = 1.0f + g1 * inv;
    __syncthreads();

    float mx = fmaxf(v0, v1);
#pragma unroll
    for (int o = 32; o; o >>= 1) mx = fmaxf(mx, __shfl_down(mx, o, 64));
    if (lane == 0) red[wv] = mx;
    __syncthreads();
    if (t == 0) red[4] = fmaxf(fmaxf(red[0], red[1]), fmaxf(red[2], red[3]));
    __syncthreads();
    float m = red[4];
    float e0 = expf(v0 - m), e1 = expf(v1 - m);
    __syncthreads();

    float se = e0 + e1;
#pragma unroll
    for (int o = 32; o; o >>= 1) se += __shfl_down(se, o, 64);
    if (lane == 0) red[wv] = se;
    __syncthreads();
    if (t == 0) red[4] = red[0] + red[1] + red[2] + red[3];
    __syncthreads();
    float is = 1.0f / red[4];
    mask[(size_t)n * CCH + t] = e0 * is;
    mask[(size_t)n * CCH + t + 256] = e1 * is;
}

// K3: blocks [0, AB) stream out = feat*mask (nt stores); blocks [AB, AB+PREDB)
// compute the pred linear (rides along with the streaming blocks for free).
__global__ __launch_bounds__(256) void k_apply(const float* __restrict__ feat,
                                               const float* __restrict__ mask,
                                               float* __restrict__ out,
                                               const float* __restrict__ pooled,
                                               const float* __restrict__ w,
                                               const float* __restrict__ b,
                                               float* __restrict__ pred) {
    __shared__ float sp[4096];
    int t = threadIdx.x;
    if (blockIdx.x < AB) {
        unsigned int i = blockIdx.x * 256u + t;             // f32x4 index, < TOT4
        unsigned int ch = i / 196u;                         // 784/4 f32x4 per channel
        float m = mask[ch];
        f32x4 v = reinterpret_cast<const f32x4*>(feat)[i];
        v.x *= m; v.y *= m; v.z *= m; v.w *= m;
        __builtin_nontemporal_store(v, reinterpret_cast<f32x4*>(out) + i);
    } else {
        int lane = t & 63, wv = t >> 6;
        int bb = (int)blockIdx.x - AB;
        int cb = bb % 250;                 // cls group (4 cls)
        int nb = bb / 250;                 // n group (8 images)
        const float* pbase = pooled + (size_t)nb * 8 * CCH;
#pragma unroll
        for (int k = 0; k < 4; ++k)        // stage 8 pooled rows (16 KB)
            *reinterpret_cast<f32x4*>(sp + k * 1024 + t * 4) =
                *reinterpret_cast<const f32x4*>(pbase + k * 1024 + t * 4);
        __syncthreads();

        int cls = cb * 4 + wv;
        const float* wr = w + (size_t)cls * CCH;
        f32x4 a0 = *reinterpret_cast<const f32x4*>(wr + lane * 8);
        f32x4 a1 = *reinterpret_cast<const f32x4*>(wr + lane * 8 + 4);
        float bias = b[cls];
        float s[8];
#pragma unroll
        for (int nn = 0; nn < 8; ++nn) {
            f32x4 p0 = *reinterpret_cast<const f32x4*>(sp + nn * CCH + lane * 8);
            f32x4 p1 = *reinterpret_cast<const f32x4*>(sp + nn * CCH + lane * 8 + 4);
            s[nn] = a0.x * p0.x + a0.y * p0.y + a0.z * p0.z + a0.w * p0.w
                  + a1.x * p1.x + a1.y * p1.y + a1.z * p1.z + a1.w * p1.w;
        }
#pragma unroll
        for (int nn = 0; nn < 8; ++nn) {
            float v = s[nn];
#pragma unroll
            for (int o = 32; o; o >>= 1) v += __shfl_down(v, o, 64);
            if (lane == 0) pred[(size_t)(nb * 8 + nn) * NCLS + cls] = v + bias;
        }
    }
}

extern "C" void kernel_launch(void* const* d_in, const int* in_sizes, int n_in,
                              void* d_out, int out_size, void* d_ws, size_t ws_size,
                              hipStream_t stream) {
    const float* feat = (const float*)d_in[0];
    const int*   y    = (const int*)d_in[1];
    const float* w    = (const float*)d_in[2];
    const float* b    = (const float*)d_in[3];

    float* out_feat = (float*)d_out;                       // 128*512*28*28
    float* out_pred = out_feat + (size_t)NB * CCH * HW;    // 128*1000

    float* pooled = (float*)d_ws;                          // 65536 floats
    float* maskp  = pooled + NB * CCH;                     // 65536 floats

    k_pool <<<(NB * CCH) / 4, 256, 0, stream>>>(feat, pooled);
    k_mask <<<NB, 256, 0, stream>>>(pooled, w, y, maskp);
    k_apply<<<AB + PREDB, 256, 0, stream>>>(feat, maskp, out_feat,
                                            pooled, w, b, out_pred);
}